// Round 11
// baseline (342.679 us; speedup 1.0000x reference)
//
#include <hip/hip_runtime.h>
#include <hip/hip_bf16.h>

// B=4, S=2048, D=1024, H=16, HD=64; M = B*S = 8192
// proj layout: chunk order is k, q, v (torch.chunk order in reference!)

typedef float f32x4 __attribute__((ext_vector_type(4)));
typedef __bf16 bf16x8 __attribute__((ext_vector_type(8)));

__device__ __forceinline__ ushort f2bf(float f) {
    uint u = __builtin_bit_cast(uint, f);
    u += 0x7fff + ((u >> 16) & 1);          // round-to-nearest-even
    return (ushort)(u >> 16);
}

#define GLL16(g, lp)                                                            \
    __builtin_amdgcn_global_load_lds(                                           \
        (const __attribute__((address_space(1))) uint*)(const void*)(g),        \
        (__attribute__((address_space(3))) uint*)(void*)(lp), 16, 0, 0)

// swizzled element offset within a [rows][64] ushort tile (128B rows):
// 16B chunk index ^= row&7  -> spreads a column-chunk across all 32 banks
#define SWZ(row, chunk) ((row) * 64 + ((((chunk) ^ ((row) & 7))) * 8))

__global__ __launch_bounds__(256) void cvt_f32_bf16(const float* __restrict__ in,
                                                    ushort* __restrict__ out, int n) {
    int i = (blockIdx.x * 256 + threadIdx.x) * 8;
    if (i >= n) return;
    float4 a = *(const float4*)&in[i];
    float4 b = *(const float4*)&in[i + 4];
    uint4 o;
    o.x = (uint)f2bf(a.x) | ((uint)f2bf(a.y) << 16);
    o.y = (uint)f2bf(a.z) | ((uint)f2bf(a.w) << 16);
    o.z = (uint)f2bf(b.x) | ((uint)f2bf(b.y) << 16);
    o.w = (uint)f2bf(b.z) | ((uint)f2bf(b.w) << 16);
    *(uint4*)&out[i] = o;
}

__global__ __launch_bounds__(256) void trans_cvt(const float* __restrict__ in,
                                                 ushort* __restrict__ out, int R, int C) {
    __shared__ float t[32][33];
    int tx = threadIdx.x & 31, ty = threadIdx.x >> 5;
    int c0 = blockIdx.x * 32, r0 = blockIdx.y * 32;
#pragma unroll
    for (int i = 0; i < 4; i++)
        t[ty + i * 8][tx] = in[(size_t)(r0 + ty + i * 8) * C + c0 + tx];
    __syncthreads();
#pragma unroll
    for (int i = 0; i < 4; i++)
        out[(size_t)(c0 + ty + i * 8) * R + r0 + tx] = f2bf(t[tx][ty + i * 8]);
}

// transpose the V third of proj into vT[bh][hd=64][s=2048] (bf16)
__global__ __launch_bounds__(256) void vtrans(const ushort* __restrict__ proj,
                                              ushort* __restrict__ vT) {
    __shared__ ushort t[128][34];
    int tid = threadIdx.x;
    int bx = blockIdx.x;
    int st = bx & 15, hdt = (bx >> 4) & 1, bh = bx >> 5;
    int b = bh >> 4, h = bh & 15;
    const ushort* src = proj + (size_t)(b * 2048 + st * 128) * 3072 + 2048 + h * 64 + hdt * 32;
    int hdx = tid & 31, sy = tid >> 5;
#pragma unroll
    for (int i = 0; i < 16; i++)
        t[sy + i * 8][hdx] = src[(size_t)(sy + i * 8) * 3072 + hdx];
    __syncthreads();
    int tx = tid & 127, ty = tid >> 7;
    ushort* dst = vT + ((size_t)bh * 64 + hdt * 32) * 2048 + st * 128;
#pragma unroll
    for (int i = 0; i < 16; i++)
        dst[(size_t)(ty + i * 2) * 2048 + tx] = t[tx][ty + i * 2];
}

// C[M,N] = A[M,K] @ Bt[N,K]^T + bias; 128x128 tile, BK=32,
// double-buffered LDS with counted vmcnt (2-phase), XCD-swizzled grid.
template <int OUTF32>
__global__ __launch_bounds__(256) void gemm_bt(const ushort* __restrict__ A,
                                               const ushort* __restrict__ Bt,
                                               const float* __restrict__ bias,
                                               void* __restrict__ Cv,
                                               int M, int N, int K) {
    __shared__ ushort As[2][128 * 32];
    __shared__ ushort Bs[2][128 * 32];
    int tid = threadIdx.x;
    int w = tid >> 6, l = tid & 63;
    int l16 = l & 15, lq = l >> 4;
    int tn = N >> 7;
    // XCD-aware bijective swizzle (gridDim.x % 8 == 0 for all our launches)
    int cpx = gridDim.x >> 3;
    int wg = (blockIdx.x & 7) * cpx + (blockIdx.x >> 3);
    int row0 = (wg / tn) * 128, col0 = (wg % tn) * 128;
    int wr = w >> 1, wc = w & 1;

    f32x4 acc[4][4];
#pragma unroll
    for (int m = 0; m < 4; m++)
#pragma unroll
        for (int n = 0; n < 4; n++) acc[m][n] = (f32x4){0.f, 0.f, 0.f, 0.f};

    int c0 = tid, c1 = tid + 256;
    const ushort* ag0 = A + (size_t)(row0 + (c0 >> 2)) * K + (c0 & 3) * 8;
    const ushort* ag1 = A + (size_t)(row0 + (c1 >> 2)) * K + (c1 & 3) * 8;
    const ushort* bg0 = Bt + (size_t)(col0 + (c0 >> 2)) * K + (c0 & 3) * 8;
    const ushort* bg1 = Bt + (size_t)(col0 + (c1 >> 2)) * K + (c1 & 3) * 8;

#define GSTAGE(bufi, kk)                                  \
    {                                                     \
        GLL16(ag0 + (kk), &As[bufi][w * 512]);            \
        GLL16(ag1 + (kk), &As[bufi][2048 + w * 512]);     \
        GLL16(bg0 + (kk), &Bs[bufi][w * 512]);            \
        GLL16(bg1 + (kk), &Bs[bufi][2048 + w * 512]);     \
    }

    int buf = 0;
    GSTAGE(0, 0);
    for (int k0 = 0; k0 < K; k0 += 32) {
        if (k0 + 32 < K) {
            GSTAGE(buf ^ 1, k0 + 32);
            asm volatile("s_waitcnt vmcnt(4)" ::: "memory");  // wait only current tile's 4 loads
        } else {
            asm volatile("s_waitcnt vmcnt(0)" ::: "memory");
        }
        __builtin_amdgcn_sched_barrier(0);
        __builtin_amdgcn_s_barrier();
        bf16x8 af[4], bfv[4];
#pragma unroll
        for (int m = 0; m < 4; m++)
            af[m] = *(const bf16x8*)&As[buf][(wr * 64 + m * 16 + l16) * 32 + lq * 8];
#pragma unroll
        for (int n = 0; n < 4; n++)
            bfv[n] = *(const bf16x8*)&Bs[buf][(wc * 64 + n * 16 + l16) * 32 + lq * 8];
#pragma unroll
        for (int m = 0; m < 4; m++)
#pragma unroll
            for (int n = 0; n < 4; n++)
                acc[m][n] = __builtin_amdgcn_mfma_f32_16x16x32_bf16(af[m], bfv[n], acc[m][n], 0, 0, 0);
        __builtin_amdgcn_s_barrier();
        buf ^= 1;
    }
#undef GSTAGE

#pragma unroll
    for (int m = 0; m < 4; m++) {
        int row = row0 + wr * 64 + m * 16 + lq * 4;
#pragma unroll
        for (int n = 0; n < 4; n++) {
            int col = col0 + wc * 64 + n * 16 + l16;
            float bv = bias[col];
#pragma unroll
            for (int r = 0; r < 4; r++) {
                float v = acc[m][n][r] + bv;
                if (OUTF32)
                    ((float*)Cv)[(size_t)(row + r) * N + col] = v;
                else
                    ((ushort*)Cv)[(size_t)(row + r) * N + col] = f2bf(v);
            }
        }
    }
}

// Flash attention, double-buffered K/V with counted vmcnt, paired q-tiles for balance,
// defer-max (skip O-rescale when per-tile max growth <= 8).
__global__ __launch_bounds__(256) void attn_kern(const ushort* __restrict__ proj,
                                                 const ushort* __restrict__ vT,
                                                 ushort* __restrict__ attno) {
    constexpr int S = 2048, TD = 3072;
    __shared__ ushort Ks[2][64 * 64];  // [buf][kv][hd] swizzled
    __shared__ ushort Vs[2][64 * 64];  // [buf][hd][kv] swizzled
    __shared__ ushort Ps[4][16 * 64];  // per-wave P [16 q][64 kv] swizzled

    int tid = threadIdx.x;
    int w = tid >> 6, l = tid & 63;
    int l16 = l & 15, lq = l >> 4;
    int bx = blockIdx.x;
    int pi = bx & 15, bh = bx >> 4;
    int b = bh >> 4, h = bh & 15;
    int qbA = pi * 64, qbB = (31 - pi) * 64;
    int nA = pi + 1;
    int ntot = 33;                     // nA + (32-pi)
    const size_t base = (size_t)b * S * TD;

    bf16x8 aqA0, aqA1, aqB0, aqB1;
    {
        const ushort* qpA = proj + base + (size_t)(qbA + w * 16 + l16) * TD + 1024 + h * 64 + lq * 8;
        aqA0 = *(const bf16x8*)(qpA);
        aqA1 = *(const bf16x8*)(qpA + 32);
        const ushort* qpB = proj + base + (size_t)(qbB + w * 16 + l16) * TD + 1024 + h * 64 + lq * 8;
        aqB0 = *(const bf16x8*)(qpB);
        aqB1 = *(const bf16x8*)(qpB + 32);
    }

    int c0 = tid, c1 = tid + 256;
    int r0 = c0 >> 3, ch0 = (c0 & 7) ^ (r0 & 7);
    int r1 = c1 >> 3, ch1 = (c1 & 7) ^ (r1 & 7);
    const ushort* kgb = proj + base + h * 64;
    const ushort* vgb = vT + (size_t)bh * 64 * 2048;

#define STAGE(bufi, j)                                                              \
    {                                                                               \
        int kb_ = (((j) < nA) ? (j) : ((j) - nA)) * 64;                             \
        GLL16(kgb + (size_t)(kb_ + r0) * TD + ch0 * 8, &Ks[bufi][w * 512]);         \
        GLL16(kgb + (size_t)(kb_ + r1) * TD + ch1 * 8, &Ks[bufi][2048 + w * 512]);  \
        GLL16(vgb + (size_t)r0 * 2048 + kb_ + ch0 * 8, &Vs[bufi][w * 512]);         \
        GLL16(vgb + (size_t)r1 * 2048 + kb_ + ch1 * 8, &Vs[bufi][2048 + w * 512]);  \
    }

    float m_r[4], lsum[4];
    f32x4 o[4];
#pragma unroll
    for (int r = 0; r < 4; r++) { m_r[r] = -1e30f; lsum[r] = 0.f; }
#pragma unroll
    for (int n = 0; n < 4; n++) o[n] = (f32x4){0.f, 0.f, 0.f, 0.f};

    bf16x8 aq0 = aqA0, aq1 = aqA1;
    int qrow_d = qbA + w * 16 + lq * 4;

    int buf = 0;
    STAGE(0, 0);

    for (int j = 0; j < ntot; j++) {
        if (j + 1 < ntot) {
            STAGE(buf ^ 1, j + 1);
            asm volatile("s_waitcnt vmcnt(4)" ::: "memory");
        } else {
            asm volatile("s_waitcnt vmcnt(0)" ::: "memory");
        }
        __builtin_amdgcn_sched_barrier(0);
        __builtin_amdgcn_s_barrier();

        if (j == nA) {
#pragma unroll
            for (int r = 0; r < 4; r++) {
                float inv = 1.0f / lsum[r];
                size_t ob = ((size_t)b * S + qrow_d + r) * 1024 + h * 64;
#pragma unroll
                for (int n = 0; n < 4; n++)
                    attno[ob + n * 16 + l16] = f2bf(o[n][r] * inv);
            }
#pragma unroll
            for (int r = 0; r < 4; r++) { m_r[r] = -1e30f; lsum[r] = 0.f; }
#pragma unroll
            for (int n = 0; n < 4; n++) o[n] = (f32x4){0.f, 0.f, 0.f, 0.f};
            aq0 = aqB0; aq1 = aqB1;
            qrow_d = qbB + w * 16 + lq * 4;
        }
        int kb = ((j < nA) ? j : (j - nA)) * 64;

        f32x4 sacc[4];
#pragma unroll
        for (int n = 0; n < 4; n++) sacc[n] = (f32x4){0.f, 0.f, 0.f, 0.f};
#pragma unroll
        for (int n = 0; n < 4; n++) {
            bf16x8 bk0 = *(const bf16x8*)&Ks[buf][SWZ(n * 16 + l16, lq)];
            bf16x8 bk1 = *(const bf16x8*)&Ks[buf][SWZ(n * 16 + l16, 4 + lq)];
            sacc[n] = __builtin_amdgcn_mfma_f32_16x16x32_bf16(aq0, bk0, sacc[n], 0, 0, 0);
            sacc[n] = __builtin_amdgcn_mfma_f32_16x16x32_bf16(aq1, bk1, sacc[n], 0, 0, 0);
        }

        float p[4][4];
#pragma unroll
        for (int n = 0; n < 4; n++) {
            int col = kb + n * 16 + l16;
#pragma unroll
            for (int r = 0; r < 4; r++) {
                float sc = sacc[n][r] * 0.125f;
                if (col > qrow_d + r) sc = -1e30f;
                p[n][r] = sc;
            }
        }

        // row maxes (4-wide per lane + 16-lane shuffle tree)
        float mx[4];
#pragma unroll
        for (int r = 0; r < 4; r++) {
            float v = fmaxf(fmaxf(p[0][r], p[1][r]), fmaxf(p[2][r], p[3][r]));
#pragma unroll
            for (int mk = 1; mk < 16; mk <<= 1) v = fmaxf(v, __shfl_xor(v, mk));
            mx[r] = v;
        }
        bool small = (mx[0] <= m_r[0] + 8.f) && (mx[1] <= m_r[1] + 8.f) &&
                     (mx[2] <= m_r[2] + 8.f) && (mx[3] <= m_r[3] + 8.f);
        if (__all(small)) {
            // defer-max: keep old max, skip O/lsum rescale
#pragma unroll
            for (int r = 0; r < 4; r++) {
                float rs = 0.f;
#pragma unroll
                for (int n = 0; n < 4; n++) {
                    float e = __expf(p[n][r] - m_r[r]);
                    p[n][r] = e;
                    rs += e;
                }
#pragma unroll
                for (int mk = 1; mk < 16; mk <<= 1) rs += __shfl_xor(rs, mk);
                lsum[r] += rs;
            }
        } else {
#pragma unroll
            for (int r = 0; r < 4; r++) {
                float mnew = fmaxf(m_r[r], mx[r]);
                float scale = __expf(m_r[r] - mnew);
                m_r[r] = mnew;
                float rs = 0.f;
#pragma unroll
                for (int n = 0; n < 4; n++) {
                    float e = __expf(p[n][r] - mnew);
                    p[n][r] = e;
                    rs += e;
                }
#pragma unroll
                for (int mk = 1; mk < 16; mk <<= 1) rs += __shfl_xor(rs, mk);
                lsum[r] = lsum[r] * scale + rs;
#pragma unroll
                for (int n = 0; n < 4; n++) o[n][r] *= scale;
            }
        }

        // P -> per-wave LDS (swizzled rows), re-read as A-fragments
#pragma unroll
        for (int n = 0; n < 4; n++) {
            int chunkbase = n * 2 + (l16 >> 3);
            int cl = l16 & 7;
#pragma unroll
            for (int r = 0; r < 4; r++) {
                int prow = lq * 4 + r;
                Ps[w][prow * 64 + ((chunkbase ^ (prow & 7)) * 8) + cl] = f2bf(p[n][r]);
            }
        }

        bf16x8 pa0 = *(const bf16x8*)&Ps[w][SWZ(l16, lq)];
        bf16x8 pa1 = *(const bf16x8*)&Ps[w][SWZ(l16, 4 + lq)];
#pragma unroll
        for (int n = 0; n < 4; n++) {
            bf16x8 bv0 = *(const bf16x8*)&Vs[buf][SWZ(n * 16 + l16, lq)];
            bf16x8 bv1 = *(const bf16x8*)&Vs[buf][SWZ(n * 16 + l16, 4 + lq)];
            o[n] = __builtin_amdgcn_mfma_f32_16x16x32_bf16(pa0, bv0, o[n], 0, 0, 0);
            o[n] = __builtin_amdgcn_mfma_f32_16x16x32_bf16(pa1, bv1, o[n], 0, 0, 0);
        }
        __builtin_amdgcn_s_barrier();
        buf ^= 1;
    }

#pragma unroll
    for (int r = 0; r < 4; r++) {
        float inv = 1.0f / lsum[r];
        size_t ob = ((size_t)b * S + qrow_d + r) * 1024 + h * 64;
#pragma unroll
        for (int n = 0; n < 4; n++)
            attno[ob + n * 16 + l16] = f2bf(o[n][r] * inv);
    }
#undef STAGE
}

extern "C" void kernel_launch(void* const* d_in, const int* in_sizes, int n_in,
                              void* d_out, int out_size, void* d_ws, size_t ws_size,
                              hipStream_t stream) {
    const float* x     = (const float*)d_in[0];
    const float* W_in  = (const float*)d_in[1];
    const float* b_in  = (const float*)d_in[2];
    const float* W_out = (const float*)d_in[3];
    const float* b_out = (const float*)d_in[4];
    float* out = (float*)d_out;
    char* ws = (char*)d_ws;

    ushort* xb    = (ushort*)(ws);                              // 16 MiB [8192][1024] (dead after gemm1)
    ushort* vT    = (ushort*)(ws);                              // 16 MiB [64bh][64hd][2048s] (reuses xb)
    ushort* w1t   = (ushort*)(ws + (size_t)16 * 1024 * 1024);   // 6 MiB  [3072][1024]
    ushort* w2t   = (ushort*)(ws + (size_t)22 * 1024 * 1024);   // 2 MiB  [1024][1024]
    ushort* proj  = (ushort*)(ws + (size_t)24 * 1024 * 1024);   // 48 MiB [8192][3072]
    ushort* attno = (ushort*)(ws + (size_t)72 * 1024 * 1024);   // 16 MiB [8192][1024]

    cvt_f32_bf16<<<4096, 256, 0, stream>>>(x, xb, 8192 * 1024);
    trans_cvt<<<dim3(96, 32), 256, 0, stream>>>(W_in, w1t, 1024, 3072);
    trans_cvt<<<dim3(32, 32), 256, 0, stream>>>(W_out, w2t, 1024, 1024);
    gemm_bt<0><<<64 * 24, 256, 0, stream>>>(xb, w1t, b_in, proj, 8192, 3072, 1024);
    vtrans<<<2048, 256, 0, stream>>>(proj, vT);
    attn_kern<<<1024, 256, 0, stream>>>(proj, vT, attno);
    gemm_bt<1><<<64 * 8, 256, 0, stream>>>(attno, w2t, b_out, out, 8192, 1024, 1024);
}

// Round 13
// 322.420 us; speedup vs baseline: 1.0628x; 1.0628x over previous
//
#include <hip/hip_runtime.h>
#include <hip/hip_bf16.h>

// B=4, S=2048, D=1024, H=16, HD=64; M = B*S = 8192
// proj layout: chunk order is k, q, v (torch.chunk order in reference!)

typedef float f32x4 __attribute__((ext_vector_type(4)));
typedef __bf16 bf16x8 __attribute__((ext_vector_type(8)));

__device__ __forceinline__ ushort f2bf(float f) {
    uint u = __builtin_bit_cast(uint, f);
    u += 0x7fff + ((u >> 16) & 1);          // round-to-nearest-even
    return (ushort)(u >> 16);
}

#define GLL16(g, lp)                                                            \
    __builtin_amdgcn_global_load_lds(                                           \
        (const __attribute__((address_space(1))) uint*)(const void*)(g),        \
        (__attribute__((address_space(3))) uint*)(void*)(lp), 16, 0, 0)

// swizzled element offset within a [rows][64] ushort tile (128B rows):
// 16B chunk index ^= row&7  -> spreads a column-chunk across all 32 banks
#define SWZ(row, chunk) ((row) * 64 + ((((chunk) ^ ((row) & 7))) * 8))

__global__ __launch_bounds__(256) void cvt_f32_bf16(const float* __restrict__ in,
                                                    ushort* __restrict__ out, int n) {
    int i = (blockIdx.x * 256 + threadIdx.x) * 8;
    if (i >= n) return;
    float4 a = *(const float4*)&in[i];
    float4 b = *(const float4*)&in[i + 4];
    uint4 o;
    o.x = (uint)f2bf(a.x) | ((uint)f2bf(a.y) << 16);
    o.y = (uint)f2bf(a.z) | ((uint)f2bf(a.w) << 16);
    o.z = (uint)f2bf(b.x) | ((uint)f2bf(b.y) << 16);
    o.w = (uint)f2bf(b.z) | ((uint)f2bf(b.w) << 16);
    *(uint4*)&out[i] = o;
}

__global__ __launch_bounds__(256) void trans_cvt(const float* __restrict__ in,
                                                 ushort* __restrict__ out, int R, int C) {
    __shared__ float t[32][33];
    int tx = threadIdx.x & 31, ty = threadIdx.x >> 5;
    int c0 = blockIdx.x * 32, r0 = blockIdx.y * 32;
#pragma unroll
    for (int i = 0; i < 4; i++)
        t[ty + i * 8][tx] = in[(size_t)(r0 + ty + i * 8) * C + c0 + tx];
    __syncthreads();
#pragma unroll
    for (int i = 0; i < 4; i++)
        out[(size_t)(c0 + ty + i * 8) * R + r0 + tx] = f2bf(t[tx][ty + i * 8]);
}

// transpose the V third of proj into vT[bh][hd=64][s=2048] (bf16)
__global__ __launch_bounds__(256) void vtrans(const ushort* __restrict__ proj,
                                              ushort* __restrict__ vT) {
    __shared__ ushort t[128][34];
    int tid = threadIdx.x;
    int bx = blockIdx.x;
    int st = bx & 15, hdt = (bx >> 4) & 1, bh = bx >> 5;
    int b = bh >> 4, h = bh & 15;
    const ushort* src = proj + (size_t)(b * 2048 + st * 128) * 3072 + 2048 + h * 64 + hdt * 32;
    int hdx = tid & 31, sy = tid >> 5;
#pragma unroll
    for (int i = 0; i < 16; i++)
        t[sy + i * 8][hdx] = src[(size_t)(sy + i * 8) * 3072 + hdx];
    __syncthreads();
    int tx = tid & 127, ty = tid >> 7;
    ushort* dst = vT + ((size_t)bh * 64 + hdt * 32) * 2048 + st * 128;
#pragma unroll
    for (int i = 0; i < 16; i++)
        dst[(size_t)(ty + i * 2) * 2048 + tx] = t[tx][ty + i * 2];
}

// C[M,N] = A[M,K] @ Bt[N,K]^T + bias; 128x128 tile, BK=32,
// double-buffered LDS with counted vmcnt (2-phase), XCD-swizzled grid.
template <int OUTF32>
__global__ __launch_bounds__(256) void gemm_bt(const ushort* __restrict__ A,
                                               const ushort* __restrict__ Bt,
                                               const float* __restrict__ bias,
                                               void* __restrict__ Cv,
                                               int M, int N, int K) {
    __shared__ ushort As[2][128 * 32];
    __shared__ ushort Bs[2][128 * 32];
    int tid = threadIdx.x;
    int w = tid >> 6, l = tid & 63;
    int l16 = l & 15, lq = l >> 4;
    int tn = N >> 7;
    // XCD-aware bijective swizzle (gridDim.x % 8 == 0 for all our launches)
    int cpx = gridDim.x >> 3;
    int wg = (blockIdx.x & 7) * cpx + (blockIdx.x >> 3);
    int row0 = (wg / tn) * 128, col0 = (wg % tn) * 128;
    int wr = w >> 1, wc = w & 1;

    f32x4 acc[4][4];
#pragma unroll
    for (int m = 0; m < 4; m++)
#pragma unroll
        for (int n = 0; n < 4; n++) acc[m][n] = (f32x4){0.f, 0.f, 0.f, 0.f};

    int c0 = tid, c1 = tid + 256;
    const ushort* ag0 = A + (size_t)(row0 + (c0 >> 2)) * K + (c0 & 3) * 8;
    const ushort* ag1 = A + (size_t)(row0 + (c1 >> 2)) * K + (c1 & 3) * 8;
    const ushort* bg0 = Bt + (size_t)(col0 + (c0 >> 2)) * K + (c0 & 3) * 8;
    const ushort* bg1 = Bt + (size_t)(col0 + (c1 >> 2)) * K + (c1 & 3) * 8;

#define GSTAGE(bufi, kk)                                  \
    {                                                     \
        GLL16(ag0 + (kk), &As[bufi][w * 512]);            \
        GLL16(ag1 + (kk), &As[bufi][2048 + w * 512]);     \
        GLL16(bg0 + (kk), &Bs[bufi][w * 512]);            \
        GLL16(bg1 + (kk), &Bs[bufi][2048 + w * 512]);     \
    }

    int buf = 0;
    GSTAGE(0, 0);
    for (int k0 = 0; k0 < K; k0 += 32) {
        if (k0 + 32 < K) {
            GSTAGE(buf ^ 1, k0 + 32);
            asm volatile("s_waitcnt vmcnt(4)" ::: "memory");  // wait only current tile's 4 loads
        } else {
            asm volatile("s_waitcnt vmcnt(0)" ::: "memory");
        }
        __builtin_amdgcn_sched_barrier(0);
        __builtin_amdgcn_s_barrier();
        bf16x8 af[4], bfv[4];
#pragma unroll
        for (int m = 0; m < 4; m++)
            af[m] = *(const bf16x8*)&As[buf][(wr * 64 + m * 16 + l16) * 32 + lq * 8];
#pragma unroll
        for (int n = 0; n < 4; n++)
            bfv[n] = *(const bf16x8*)&Bs[buf][(wc * 64 + n * 16 + l16) * 32 + lq * 8];
#pragma unroll
        for (int m = 0; m < 4; m++)
#pragma unroll
            for (int n = 0; n < 4; n++)
                acc[m][n] = __builtin_amdgcn_mfma_f32_16x16x32_bf16(af[m], bfv[n], acc[m][n], 0, 0, 0);
        __builtin_amdgcn_s_barrier();
        buf ^= 1;
    }
#undef GSTAGE

#pragma unroll
    for (int m = 0; m < 4; m++) {
        int row = row0 + wr * 64 + m * 16 + lq * 4;
#pragma unroll
        for (int n = 0; n < 4; n++) {
            int col = col0 + wc * 64 + n * 16 + l16;
            float bv = bias[col];
#pragma unroll
            for (int r = 0; r < 4; r++) {
                float v = acc[m][n][r] + bv;
                if (OUTF32)
                    ((float*)Cv)[(size_t)(row + r) * N + col] = v;
                else
                    ((ushort*)Cv)[(size_t)(row + r) * N + col] = f2bf(v);
            }
        }
    }
}

// Flash attention, double-buffered K/V with counted vmcnt, paired q-tiles for balance.
// Softmax in exp2 domain; causal mask applied only on the (wave-uniform) diagonal tile.
__global__ __launch_bounds__(256) void attn_kern(const ushort* __restrict__ proj,
                                                 const ushort* __restrict__ vT,
                                                 ushort* __restrict__ attno) {
    constexpr int S = 2048, TD = 3072;
    constexpr float S2 = 0.125f * 1.44269504088896f;  // 1/sqrt(64) * log2(e)
    __shared__ ushort Ks[2][64 * 64];  // [buf][kv][hd] swizzled
    __shared__ ushort Vs[2][64 * 64];  // [buf][hd][kv] swizzled
    __shared__ ushort Ps[4][16 * 64];  // per-wave P [16 q][64 kv] swizzled

    int tid = threadIdx.x;
    int w = tid >> 6, l = tid & 63;
    int l16 = l & 15, lq = l >> 4;
    int bx = blockIdx.x;
    int pi = bx & 15, bh = bx >> 4;
    int b = bh >> 4, h = bh & 15;
    int qbA = pi * 64, qbB = (31 - pi) * 64;
    int nA = pi + 1;
    int ntot = 33;                     // nA + (32-pi)
    const size_t base = (size_t)b * S * TD;

    bf16x8 aqA0, aqA1, aqB0, aqB1;
    {
        const ushort* qpA = proj + base + (size_t)(qbA + w * 16 + l16) * TD + 1024 + h * 64 + lq * 8;
        aqA0 = *(const bf16x8*)(qpA);
        aqA1 = *(const bf16x8*)(qpA + 32);
        const ushort* qpB = proj + base + (size_t)(qbB + w * 16 + l16) * TD + 1024 + h * 64 + lq * 8;
        aqB0 = *(const bf16x8*)(qpB);
        aqB1 = *(const bf16x8*)(qpB + 32);
    }

    int c0 = tid, c1 = tid + 256;
    int r0 = c0 >> 3, ch0 = (c0 & 7) ^ (r0 & 7);
    int r1 = c1 >> 3, ch1 = (c1 & 7) ^ (r1 & 7);
    const ushort* kgb = proj + base + h * 64;
    const ushort* vgb = vT + (size_t)bh * 64 * 2048;

#define STAGE(bufi, j)                                                              \
    {                                                                               \
        int kb_ = (((j) < nA) ? (j) : ((j) - nA)) * 64;                             \
        GLL16(kgb + (size_t)(kb_ + r0) * TD + ch0 * 8, &Ks[bufi][w * 512]);         \
        GLL16(kgb + (size_t)(kb_ + r1) * TD + ch1 * 8, &Ks[bufi][2048 + w * 512]);  \
        GLL16(vgb + (size_t)r0 * 2048 + kb_ + ch0 * 8, &Vs[bufi][w * 512]);         \
        GLL16(vgb + (size_t)r1 * 2048 + kb_ + ch1 * 8, &Vs[bufi][2048 + w * 512]);  \
    }

    float m_r[4], lsum[4];
    f32x4 o[4];
#pragma unroll
    for (int r = 0; r < 4; r++) { m_r[r] = -1e30f; lsum[r] = 0.f; }
#pragma unroll
    for (int n = 0; n < 4; n++) o[n] = (f32x4){0.f, 0.f, 0.f, 0.f};

    bf16x8 aq0 = aqA0, aq1 = aqA1;
    int qrow_d = qbA + w * 16 + lq * 4;
    int qbt = qbA;

    int buf = 0;
    STAGE(0, 0);

    for (int j = 0; j < ntot; j++) {
        if (j + 1 < ntot) {
            STAGE(buf ^ 1, j + 1);
            asm volatile("s_waitcnt vmcnt(4)" ::: "memory");
        } else {
            asm volatile("s_waitcnt vmcnt(0)" ::: "memory");
        }
        __builtin_amdgcn_sched_barrier(0);
        __builtin_amdgcn_s_barrier();

        if (j == nA) {
#pragma unroll
            for (int r = 0; r < 4; r++) {
                float inv = 1.0f / lsum[r];
                size_t ob = ((size_t)b * S + qrow_d + r) * 1024 + h * 64;
#pragma unroll
                for (int n = 0; n < 4; n++)
                    attno[ob + n * 16 + l16] = f2bf(o[n][r] * inv);
            }
#pragma unroll
            for (int r = 0; r < 4; r++) { m_r[r] = -1e30f; lsum[r] = 0.f; }
#pragma unroll
            for (int n = 0; n < 4; n++) o[n] = (f32x4){0.f, 0.f, 0.f, 0.f};
            aq0 = aqB0; aq1 = aqB1;
            qrow_d = qbB + w * 16 + lq * 4;
            qbt = qbB;
        }
        int kb = ((j < nA) ? j : (j - nA)) * 64;

        f32x4 sacc[4];
#pragma unroll
        for (int n = 0; n < 4; n++) sacc[n] = (f32x4){0.f, 0.f, 0.f, 0.f};
#pragma unroll
        for (int n = 0; n < 4; n++) {
            bf16x8 bk0 = *(const bf16x8*)&Ks[buf][SWZ(n * 16 + l16, lq)];
            bf16x8 bk1 = *(const bf16x8*)&Ks[buf][SWZ(n * 16 + l16, 4 + lq)];
            sacc[n] = __builtin_amdgcn_mfma_f32_16x16x32_bf16(aq0, bk0, sacc[n], 0, 0, 0);
            sacc[n] = __builtin_amdgcn_mfma_f32_16x16x32_bf16(aq1, bk1, sacc[n], 0, 0, 0);
        }

        float p[4][4];
#pragma unroll
        for (int n = 0; n < 4; n++)
#pragma unroll
            for (int r = 0; r < 4; r++)
                p[n][r] = sacc[n][r] * S2;           // log2-domain scores

        if (kb == qbt) {                             // diagonal tile only (wave-uniform)
#pragma unroll
            for (int n = 0; n < 4; n++) {
                int col = kb + n * 16 + l16;
#pragma unroll
                for (int r = 0; r < 4; r++)
                    if (col > qrow_d + r) p[n][r] = -1e30f;
            }
        }

#pragma unroll
        for (int r = 0; r < 4; r++) {
            float mxv = fmaxf(fmaxf(p[0][r], p[1][r]), fmaxf(p[2][r], p[3][r]));
#pragma unroll
            for (int mk = 1; mk < 16; mk <<= 1) mxv = fmaxf(mxv, __shfl_xor(mxv, mk));
            float mnew = fmaxf(m_r[r], mxv);
            float scale = __builtin_amdgcn_exp2f(m_r[r] - mnew);
            m_r[r] = mnew;
            float rs = 0.f;
#pragma unroll
            for (int n = 0; n < 4; n++) {
                float e = __builtin_amdgcn_exp2f(p[n][r] - mnew);
                p[n][r] = e;
                rs += e;
            }
#pragma unroll
            for (int mk = 1; mk < 16; mk <<= 1) rs += __shfl_xor(rs, mk);
            lsum[r] = lsum[r] * scale + rs;
#pragma unroll
            for (int n = 0; n < 4; n++) o[n][r] *= scale;
        }

        // P -> per-wave LDS (swizzled rows), re-read as A-fragments
#pragma unroll
        for (int n = 0; n < 4; n++) {
            int chunkbase = n * 2 + (l16 >> 3);
            int cl = l16 & 7;
#pragma unroll
            for (int r = 0; r < 4; r++) {
                int prow = lq * 4 + r;
                Ps[w][prow * 64 + ((chunkbase ^ (prow & 7)) * 8) + cl] = f2bf(p[n][r]);
            }
        }

        bf16x8 pa0 = *(const bf16x8*)&Ps[w][SWZ(l16, lq)];
        bf16x8 pa1 = *(const bf16x8*)&Ps[w][SWZ(l16, 4 + lq)];
#pragma unroll
        for (int n = 0; n < 4; n++) {
            bf16x8 bv0 = *(const bf16x8*)&Vs[buf][SWZ(n * 16 + l16, lq)];
            bf16x8 bv1 = *(const bf16x8*)&Vs[buf][SWZ(n * 16 + l16, 4 + lq)];
            o[n] = __builtin_amdgcn_mfma_f32_16x16x32_bf16(pa0, bv0, o[n], 0, 0, 0);
            o[n] = __builtin_amdgcn_mfma_f32_16x16x32_bf16(pa1, bv1, o[n], 0, 0, 0);
        }
        __builtin_amdgcn_s_barrier();
        buf ^= 1;
    }

#pragma unroll
    for (int r = 0; r < 4; r++) {
        float inv = 1.0f / lsum[r];
        size_t ob = ((size_t)b * S + qrow_d + r) * 1024 + h * 64;
#pragma unroll
        for (int n = 0; n < 4; n++)
            attno[ob + n * 16 + l16] = f2bf(o[n][r] * inv);
    }
#undef STAGE
}

extern "C" void kernel_launch(void* const* d_in, const int* in_sizes, int n_in,
                              void* d_out, int out_size, void* d_ws, size_t ws_size,
                              hipStream_t stream) {
    const float* x     = (const float*)d_in[0];
    const float* W_in  = (const float*)d_in[1];
    const float* b_in  = (const float*)d_in[2];
    const float* W_out = (const float*)d_in[3];
    const float* b_out = (const float*)d_in[4];
    float* out = (float*)d_out;
    char* ws = (char*)d_ws;

    ushort* xb    = (ushort*)(ws);                              // 16 MiB [8192][1024] (dead after gemm1)
    ushort* vT    = (ushort*)(ws);                              // 16 MiB [64bh][64hd][2048s] (reuses xb)
    ushort* w1t   = (ushort*)(ws + (size_t)16 * 1024 * 1024);   // 6 MiB  [3072][1024]
    ushort* w2t   = (ushort*)(ws + (size_t)22 * 1024 * 1024);   // 2 MiB  [1024][1024]
    ushort* proj  = (ushort*)(ws + (size_t)24 * 1024 * 1024);   // 48 MiB [8192][3072]
    ushort* attno = (ushort*)(ws + (size_t)72 * 1024 * 1024);   // 16 MiB [8192][1024]

    cvt_f32_bf16<<<4096, 256, 0, stream>>>(x, xb, 8192 * 1024);
    trans_cvt<<<dim3(96, 32), 256, 0, stream>>>(W_in, w1t, 1024, 3072);
    trans_cvt<<<dim3(32, 32), 256, 0, stream>>>(W_out, w2t, 1024, 1024);
    gemm_bt<0><<<64 * 24, 256, 0, stream>>>(xb, w1t, b_in, proj, 8192, 3072, 1024);
    vtrans<<<2048, 256, 0, stream>>>(proj, vT);
    attn_kern<<<1024, 256, 0, stream>>>(proj, vT, attno);
    gemm_bt<1><<<64 * 8, 256, 0, stream>>>(attno, w2t, b_out, out, 8192, 1024, 1024);
}